// Round 8
// baseline (203.168 us; speedup 1.0000x reference)
//
#include <hip/hip_runtime.h>

// MoE-LoRA top-1 dispatch.
//  cvt_a: lora_A f32 -> Apack bf16 in MFMA-fragment order (e,ks,n,lane)
//  cvt_b: lora_B f32 -> Bbf bf16 linear
//  xe:    per (sb,b,e) block: pool quarter (no barriers) + x@A^T direct-from-global
//         MFMA (no LDS, no barriers) -> xr_all bf16
//  router: partials -> MLP -> top/balance ; out: xr[top[b]] @ B^T * 2
constexpr int B_ = 4, S_ = 2048, D_ = 4096, E_ = 4, R_ = 64, OUT_ = 4096;
constexpr int NMOD = 4, NREG = 3, HID_ = 128;
constexpr int RIN_ = D_ + NMOD + NREG;      // 4103
constexpr float SCALING_ = 2.0f;            // alpha/rank
constexpr int NKS_ = D_ / 32;               // 128 k-steps of 32
constexpr int P_   = 128;                   // pool partials: 32 sb x 4 e-quarters
constexpr int KC_  = 33;                    // router k-chunks of 128 (33*128 >= 4103)

// ws layout (float units) — everything fully written each call, no memset needed
constexpr size_t WS_PP    = 0;                                     // P_*B*D f32 pool partials
constexpr size_t WS_HACC2 = WS_PP + (size_t)P_ * B_ * D_;          // B*KC_*HID f32
constexpr size_t WS_TOP   = WS_HACC2 + B_ * KC_ * HID_;            // B ints
constexpr size_t WS_APK   = WS_TOP + 16;                           // E*R*D bf16 (packed frags)
constexpr size_t WS_BBF   = WS_APK + (size_t)E_ * R_ * D_ / 2;     // E*OUT*R bf16
constexpr size_t WS_XRB   = WS_BBF + (size_t)E_ * OUT_ * R_ / 2;   // E*B*S*R bf16

using short8 = __attribute__((ext_vector_type(8))) short;
using f32x4  = __attribute__((ext_vector_type(4))) float;
union frag_u { int4 i4; short8 s8; };

__device__ inline unsigned short f2bf(float f) {  // RNE fp32 -> bf16
    unsigned u = __float_as_uint(f);
    unsigned r = u + 0x7FFFu + ((u >> 16) & 1u);
    return (unsigned short)(r >> 16);
}

// Apack[(((e*128+ks)*4+n)*64+lane)*8 + j] = A[e][n*16+(lane&15)][ks*32+(lane>>4)*8+j]
__global__ __launch_bounds__(256) void cvt_a_kernel(const float* __restrict__ A,
                                                    ushort* __restrict__ Apack) {
    int idx  = blockIdx.x * 256 + threadIdx.x;   // E*128*4*64 = 131072
    int lane = idx & 63, n = (idx >> 6) & 3, ks = (idx >> 8) & 127, e = idx >> 15;
    const float* src = A + ((size_t)e * R_ + n * 16 + (lane & 15)) * D_
                         + ks * 32 + (lane >> 4) * 8;
    ushort* dst = Apack + (size_t)idx * 8;
    float4 v0 = *(const float4*)(src);
    float4 v1 = *(const float4*)(src + 4);
    *(ushort4*)(dst)     = make_ushort4(f2bf(v0.x), f2bf(v0.y), f2bf(v0.z), f2bf(v0.w));
    *(ushort4*)(dst + 4) = make_ushort4(f2bf(v1.x), f2bf(v1.y), f2bf(v1.z), f2bf(v1.w));
}

__global__ __launch_bounds__(256) void cvt_b_kernel(const float* __restrict__ Bw,
                                                    ushort* __restrict__ Bbf) {
    int i = blockIdx.x * 256 + threadIdx.x;      // float4 id, E*OUT*R/4
    float4 v = ((const float4*)Bw)[i];
    ((ushort4*)Bbf)[i] = make_ushort4(f2bf(v.x), f2bf(v.y), f2bf(v.z), f2bf(v.w));
}

// Block (sb,b,e): NO LDS, NO BARRIERS.
// Phase 1: pool partial over rows [s0+e*16, s0+e*16+16)  (block-local quarter).
// Phase 2: 4 waves; wave w = m-tile rows s0+w*16..+16, all 4 n-tiles, full D.
//          x frags loaded direct from global (f32 -> cvt_pk bf16), A frags from Apack.
__global__ __launch_bounds__(256) void xe_kernel(const float* __restrict__ x,
                                                 const ushort* __restrict__ Apack,
                                                 float* __restrict__ pp,
                                                 ushort* __restrict__ xr_bf) {
    int sb = blockIdx.x, b = blockIdx.y, e = blockIdx.z;
    int s0 = sb * 64;
    int t = threadIdx.x, lane = t & 63, w = t >> 6;

    // ---- pool quarter (coalesced float4 stream, per-thread accumulators) ----
    {
        const float4* xp = (const float4*)(x + ((size_t)b * S_ + s0 + e * 16) * D_);
        float4 a0 = {0,0,0,0}, a1 = {0,0,0,0}, a2 = {0,0,0,0}, a3 = {0,0,0,0};
#pragma unroll 4
        for (int r = 0; r < 16; ++r) {
            float4 v0 = xp[(size_t)r * 1024 + t];
            float4 v1 = xp[(size_t)r * 1024 + 256 + t];
            float4 v2 = xp[(size_t)r * 1024 + 512 + t];
            float4 v3 = xp[(size_t)r * 1024 + 768 + t];
            a0.x += v0.x; a0.y += v0.y; a0.z += v0.z; a0.w += v0.w;
            a1.x += v1.x; a1.y += v1.y; a1.z += v1.z; a1.w += v1.w;
            a2.x += v2.x; a2.y += v2.y; a2.z += v2.z; a2.w += v2.w;
            a3.x += v3.x; a3.y += v3.y; a3.z += v3.z; a3.w += v3.w;
        }
        float* ppb = pp + ((size_t)(sb * E_ + e) * B_ + b) * D_;
        *(float4*)&ppb[(t)       * 4] = a0;
        *(float4*)&ppb[(256 + t) * 4] = a1;
        *(float4*)&ppb[(512 + t) * 4] = a2;
        *(float4*)&ppb[(768 + t) * 4] = a3;
    }

    // ---- MFMA phase: barrier-free k-loop ----
    const float* xrow = x + ((size_t)b * S_ + s0 + w * 16 + (lane & 15)) * D_
                          + (lane >> 4) * 8;
    const int4* ap = (const int4*)Apack + ((size_t)e * NKS_ * 4) * 64 + lane;
    f32x4 acc[4] = {};
#pragma unroll 4
    for (int ks = 0; ks < NKS_; ++ks) {
        float4 v0 = *(const float4*)(xrow + ks * 32);
        float4 v1 = *(const float4*)(xrow + ks * 32 + 4);
        unsigned r0, r1, r2, r3;
        asm("v_cvt_pk_bf16_f32 %0, %1, %2" : "=v"(r0) : "v"(v0.x), "v"(v0.y));
        asm("v_cvt_pk_bf16_f32 %0, %1, %2" : "=v"(r1) : "v"(v0.z), "v"(v0.w));
        asm("v_cvt_pk_bf16_f32 %0, %1, %2" : "=v"(r2) : "v"(v1.x), "v"(v1.y));
        asm("v_cvt_pk_bf16_f32 %0, %1, %2" : "=v"(r3) : "v"(v1.z), "v"(v1.w));
        frag_u xa; xa.i4 = make_int4(r0, r1, r2, r3);
#pragma unroll
        for (int n = 0; n < 4; ++n) {
            frag_u bf; bf.i4 = ap[(size_t)ks * 256 + n * 64];
            acc[n] = __builtin_amdgcn_mfma_f32_16x16x32_bf16(xa.s8, bf.s8, acc[n], 0, 0, 0);
        }
    }
    // C/D: col = lane&15, row = (lane>>4)*4 + i
    int col0 = lane & 15;
    int rb   = w * 16 + ((lane >> 4) << 2);
    ushort* xo = xr_bf + (((size_t)e * B_ + b) * S_ + s0) * R_;
#pragma unroll
    for (int n = 0; n < 4; ++n)
#pragma unroll
        for (int i = 0; i < 4; ++i)
            xo[(size_t)(rb + i) * R_ + n * 16 + col0] = f2bf(acc[n][i]);
}

// hacc2[b][kc][h] = sum over chunk's 128 k-rows of router_in[k]*w1[k][h]
__global__ __launch_bounds__(256) void router_h_kernel(const float* __restrict__ pp,
                                                       const float* __restrict__ rel,
                                                       const float* __restrict__ reg,
                                                       const float* __restrict__ w1,
                                                       float* __restrict__ hacc2) {
    __shared__ float rin[128];
    __shared__ float red[256];
    int b = blockIdx.x, kc = blockIdx.y;
    int t = threadIdx.x;
    int k0 = kc * 128;
    // parallel partial-sum: thread t covers column k0+(t&127), partials half (t>>7)
    {
        int k = k0 + (t & 127), half = t >> 7;
        float s = 0.f;
        if (k < D_) {
            for (int pi = half * 64; pi < half * 64 + 64; ++pi)
                s += pp[((size_t)pi * B_ + b) * D_ + k];
        }
        red[t] = s;
    }
    __syncthreads();
    if (t < 128) {
        int k = k0 + t;
        float v = 0.f;
        if (k < D_)               v = (red[t] + red[t + 128]) * (1.0f / S_);
        else if (k < D_ + NMOD)   v = rel[b * NMOD + (k - D_)];
        else if (k < RIN_)        v = reg[b * NREG + (k - D_ - NMOD)];
        rin[t] = v;
    }
    __syncthreads();
    int h = t & 127, half = t >> 7;
    float acc = 0.f;
#pragma unroll 8
    for (int i = 0; i < 64; ++i) {
        int kk = 2 * i + half;
        int k = k0 + kk;
        if (k < RIN_) acc += rin[kk] * w1[(size_t)k * HID_ + h];
    }
    red[t] = acc;
    __syncthreads();
    if (t < 128)
        hacc2[((size_t)b * KC_ + kc) * HID_ + t] = red[t] + red[t + 128];
}

__global__ void router_finish_kernel(const float* __restrict__ hacc2, const float* __restrict__ b1,
                                     const float* __restrict__ w2, const float* __restrict__ b2,
                                     int* __restrict__ top, float* __restrict__ bal_out) {
    __shared__ float h_lds[B_][HID_];
    __shared__ float logit[B_][E_];
    __shared__ float probs[B_][E_];
    int t = threadIdx.x; // 128
    for (int b = 0; b < B_; ++b) {
        float v = b1[t];
        for (int j = 0; j < KC_; ++j) v += hacc2[((size_t)b * KC_ + j) * HID_ + t];
        float u = 0.7978845608028654f * (v + 0.044715f * v * v * v); // tanh-GELU
        h_lds[b][t] = 0.5f * v * (1.0f + tanhf(u));
    }
    __syncthreads();
    if (t < B_ * E_) {
        int b = t >> 2, e = t & 3;
        float acc = b2[e];
        for (int j = 0; j < HID_; ++j) acc += h_lds[b][j] * w2[j * E_ + e];
        logit[b][e] = acc;
    }
    __syncthreads();
    if (t < B_) {
        int b = t;
        float m = logit[b][0]; int arg = 0;
        for (int e = 1; e < E_; ++e) if (logit[b][e] > m) { m = logit[b][e]; arg = e; }
        float s = 0.f, pv[E_];
        for (int e = 0; e < E_; ++e) { pv[e] = expf(logit[b][e] - m); s += pv[e]; }
        for (int e = 0; e < E_; ++e) probs[b][e] = pv[e] / s;
        top[b] = arg;
    }
    __syncthreads();
    if (t == 0) {
        float bal = 0.f;
        for (int e = 0; e < E_; ++e) {
            float avg = 0.25f * (probs[0][e] + probs[1][e] + probs[2][e] + probs[3][e]);
            bal += avg * avg;
        }
        *bal_out = 0.01f * E_ * bal;
    }
}

// out[b,s,o] = 2 * sum_r xr_bf[top[b]][b,s,r] * B_bf[e,o,r]
__global__ __launch_bounds__(256) void out_kernel(const ushort* __restrict__ xr_bf,
                                                  const ushort* __restrict__ Bbf,
                                                  const int* __restrict__ top,
                                                  float* __restrict__ out) {
    __shared__ ushort xrs[64][72];
    __shared__ ushort bs[128][72];
    int b  = blockIdx.z;
    int e  = top[b];
    int s0 = blockIdx.x * 64, o0 = blockIdx.y * 128;
    int t = threadIdx.x, lane = t & 63, w = t >> 6;
    const ushort* xrb = xr_bf + (((size_t)e * B_ + b) * S_ + s0) * R_;
#pragma unroll
    for (int i = 0; i < 2; ++i) {                   // stage xr 64x64 bf16
        int lin = t + 256 * i; int row = lin >> 3, cq = lin & 7;
        int4 v = *(const int4*)(xrb + (size_t)row * R_ + cq * 8);
        *(int4*)&xrs[row][cq * 8] = v;
    }
    const ushort* Bb = Bbf + (size_t)e * OUT_ * R_ + (size_t)o0 * R_;
#pragma unroll
    for (int i = 0; i < 4; ++i) {                   // stage B 128x64 bf16
        int lin = t + 256 * i; int row = lin >> 3, cq = lin & 7;
        int4 v = *(const int4*)(Bb + (size_t)row * R_ + cq * 8);
        *(int4*)&bs[row][cq * 8] = v;
    }
    __syncthreads();
    int mrow = w * 16 + (lane & 15);
    int koff = (lane >> 4) * 8;
    f32x4 acc[8] = {};
#pragma unroll
    for (int kk = 0; kk < 2; ++kk) {
        short8 af = *(const short8*)&xrs[mrow][kk * 32 + koff];
#pragma unroll
        for (int n = 0; n < 8; ++n) {
            short8 bf = *(const short8*)&bs[n * 16 + (lane & 15)][kk * 32 + koff];
            acc[n] = __builtin_amdgcn_mfma_f32_16x16x32_bf16(af, bf, acc[n], 0, 0, 0);
        }
    }
    int col0  = lane & 15;
    int rbase = (lane >> 4) << 2;
    float* ob = out + ((size_t)b * S_ + s0 + w * 16) * OUT_ + o0;
#pragma unroll
    for (int n = 0; n < 8; ++n)
#pragma unroll
        for (int i = 0; i < 4; ++i)
            ob[(size_t)(rbase + i) * OUT_ + n * 16 + col0] = acc[n][i] * SCALING_;
}

extern "C" void kernel_launch(void* const* d_in, const int* in_sizes, int n_in,
                              void* d_out, int out_size, void* d_ws, size_t ws_size,
                              hipStream_t stream) {
    const float* x   = (const float*)d_in[0];
    const float* rel = (const float*)d_in[1];
    const float* reg = (const float*)d_in[2];
    const float* lA  = (const float*)d_in[3];
    const float* lB  = (const float*)d_in[4];
    const float* w1  = (const float*)d_in[5];
    const float* b1  = (const float*)d_in[6];
    const float* w2  = (const float*)d_in[7];
    const float* b2  = (const float*)d_in[8];
    float* out = (float*)d_out;
    float* ws  = (float*)d_ws;

    float*  pp    = ws + WS_PP;
    float*  hacc2 = ws + WS_HACC2;
    int*    top   = (int*)(ws + WS_TOP);
    ushort* Apk   = (ushort*)(ws + WS_APK);
    ushort* Bbf   = (ushort*)(ws + WS_BBF);
    ushort* xrb   = (ushort*)(ws + WS_XRB);

    cvt_a_kernel<<<E_ * NKS_ * 4 * 64 / 256, 256, 0, stream>>>(lA, Apk);
    cvt_b_kernel<<<E_ * OUT_ * R_ / 4 / 256, 256, 0, stream>>>(lB, Bbf);
    xe_kernel<<<dim3(S_ / 64, B_, E_), 256, 0, stream>>>(x, Apk, pp, xrb);
    router_h_kernel<<<dim3(B_, KC_), 256, 0, stream>>>(pp, rel, reg, w1, hacc2);
    router_finish_kernel<<<1, 128, 0, stream>>>(hacc2, b1, w2, b2, top,
                                                out + (size_t)out_size - 1);
    out_kernel<<<dim3(S_ / 64, OUT_ / 128, B_), 256, 0, stream>>>(xrb, Bbf, top, out);
}